// Round 16
// baseline (844.906 us; speedup 1.0000x reference)
//
#include <hip/hip_runtime.h>
#include <hip/hip_bf16.h>
#include <stdint.h>

// HierarchicalGNN forward, FP32 in/out, MFMA bf16 GEMMs, CSR-gather GAT (no f32 atomics).
// h=relu(x@Wp+bp); two GATConv(+selfloops, softmax-per-dst) -> LN -> relu;
// concat @ Wf -> LN -> L2-normalize.
// N=200000, E=200000/dir (avg degree ~1), IN=HID=256, HEADS=4, C=64, OUT=128.
// Structure: transpose_all also zeroes cnt/cur (was memset); gemm1 prologue does the
// edge histogram (was hist_dst2; cnt zeroed by PREVIOUS kernel - stream order);
// ONE merged dir GEMM (gemm_dir2, A+B dbuf 80 KB) -> [N,512] concat + fused att
// scores; COMBINED 2N-virtual-node CSR (scan1/scan2/finalize/scatter only);
// gat_gather computes per-head softmax INLINE (max pass, sum pass, gather pass;
// deg~1) - att_alpha kernel and alpha buffers eliminated; final GEMM fused
// bias+LN+L2norm.
// LESSONS: B must be LDS-staged ahead (R13 -19%); counted-vmcnt regresses at 2-phase
// (R10); MODE=2 needs non-null gw/bw (R6/R7 fault); edge prefetch in gather = null (R15).

typedef __attribute__((ext_vector_type(8))) short bf16x8;
typedef __attribute__((ext_vector_type(4))) short bf16x4;
typedef __attribute__((ext_vector_type(4))) float f32x4;

#define HID 256

__device__ __forceinline__ float red16(float v) {   // sum within 16-lane group
    #pragma unroll
    for (int o = 1; o < 16; o <<= 1) v += __shfl_xor(v, o, 64);
    return v;
}
__device__ __forceinline__ float bf2f(short s) {
    return __uint_as_float(((unsigned)(unsigned short)s) << 16);
}
__device__ __forceinline__ float lrelu(float e) { return e > 0.f ? e : 0.2f * e; }

// async global->LDS, 16B per lane (global_load_lds_dwordx4).
__device__ __forceinline__ void gload_lds16(const void* g, void* l) {
    __builtin_amdgcn_global_load_lds(
        reinterpret_cast<const __attribute__((address_space(1))) uint32_t*>(
            reinterpret_cast<uintptr_t>(g)),
        reinterpret_cast<__attribute__((address_space(3))) uint32_t*>(
            reinterpret_cast<uintptr_t>(l)),
        16, 0, 0);
}

// ------- fused: all four weight transposes + zero cnt/cur, one launch -------
// weights: [0,64K) Wp->Wpt; [64K,128K) W_bu->Wcat[0:256]; [128K,192K) W_td->Wcat[256:];
// [192K,256K) Wf[512,128]->Wft. Also cnt0[idx]=0 for idx < nZero (cnt|cur adjacent).
__global__ __launch_bounds__(256) void transpose_all(
    const float* __restrict__ Wp, const float* __restrict__ Wbu,
    const float* __restrict__ Wtd, const float* __restrict__ Wf,
    __hip_bfloat16* __restrict__ Wpt, __hip_bfloat16* __restrict__ Wcat,
    __hip_bfloat16* __restrict__ Wft, int* __restrict__ zeroPtr, int nZero) {
    int idx = blockIdx.x * 256 + threadIdx.x;
    if (idx < nZero) zeroPtr[idx] = 0;
    if (idx < 65536) {
        int k = idx >> 8, j = idx & 255;
        Wpt[j * 256 + k] = __float2bfloat16(Wp[idx]);
    } else if (idx < 131072) {
        int t = idx - 65536; int k = t >> 8, j = t & 255;
        Wcat[j * 256 + k] = __float2bfloat16(Wbu[t]);
    } else if (idx < 196608) {
        int t = idx - 131072; int k = t >> 8, j = t & 255;
        Wcat[65536 + j * 256 + k] = __float2bfloat16(Wtd[t]);
    } else if (idx < 262144) {
        int t = idx - 196608; int k = t >> 7, j = t & 127;   // KI=512, KO=128
        Wft[(long)j * 512 + k] = __float2bfloat16(Wf[t]);
    }
}

// ---------------- tiled MFMA GEMM: C[N,BN] = A[N,KI] @ Bt[BN,KI]^T ----------------
// BM=128, BK=32, double-buffered LDS (A and B); B via global_load_lds_dwordx4;
// A via gload (CVT=0) or reg-staged f32->bf16 (CVT=1). 512 threads = 8 waves.
// MODE 0: +bias/relu -> bf16 out; optionally does edge histogram in prologue
//         (cntH != nullptr; requires cnt zeroed by a PRIOR kernel on the stream).
// MODE 2: fused +bias -> LN(128) -> L2-normalize -> f32 out (BN=128)
template<int BN, int MODE, int CVT>
__global__ __launch_bounds__(512) void gemm_tiled(
    const float* __restrict__ Af, const __hip_bfloat16* __restrict__ Ab, int lda,
    const __hip_bfloat16* __restrict__ Bt, int KI,
    const float* __restrict__ bias, int doRelu,
    __hip_bfloat16* __restrict__ outB, int ldcB, int colOff,
    float* __restrict__ outF,
    const float* __restrict__ gw, const float* __restrict__ bw,
    const int* __restrict__ ei0, const int* __restrict__ ei1, int E,
    int* __restrict__ cntH, int N) {

    constexpr int WN = BN / 64;          // waves along N (4 or 2)
    constexpr int WM = 8 / WN;           // waves along M (2 or 4)
    constexpr int MR = (128 / WM) / 16;  // m-frags per wave (4 or 2)

    __shared__ __align__(16) __hip_bfloat16 sA[2][128 * 32];  // [buf][row][k] 64B rows
    __shared__ __align__(16) __hip_bfloat16 sB[2][BN * 32];   // [buf][col][k] 64B rows
    __shared__ float sRed[MODE == 2 ? 128 * 4 : 4];
    __shared__ float sN2[MODE == 2 ? 128 * 2 : 2];

    int tid = threadIdx.x;

    // fused edge histogram (MODE 0): 800K threads cover 2E=400K edges; overlaps GEMM.
    if constexpr (MODE == 0) {
        if (cntH) {
            int e = blockIdx.x * 512 + tid;
            if (e < E) atomicAdd(&cntH[ei0[E + e]], 1);
            else if (e < 2 * E) atomicAdd(&cntH[ei1[e] + N], 1);  // ei1[E+(e-E)] = dst_td
        }
    }

    int wv = tid >> 6, ln = tid & 63;
    int m = ln & 15, q = ln >> 4;
    long row0 = (long)blockIdx.x * 128;
    int wr = (wv / WN) * (128 / WM);
    int wc = (wv % WN) * 64;

    f32x4 acc[MR][4];
    #pragma unroll
    for (int mi = 0; mi < MR; ++mi)
        #pragma unroll
        for (int t = 0; t < 4; ++t) acc[mi][t] = (f32x4){0.f, 0.f, 0.f, 0.f};

    int oA = tid * 16;                   // dest byte in sA buf (8 KB total)
    long rowA = row0 + (oA >> 6);
    if (rowA >= N) rowA = N - 1;         // clamp tail loads (dup reads, safe)
    int kel = (oA & 63) >> 1;            // element offset in 32-elem k-chunk
    long aBase = rowA * (long)lda + kel;

    auto stage = [&](int buf, int k0) {
        if constexpr (CVT) {
            const float* src = Af + aBase + k0;
            f32x4 fa0 = *(const f32x4*)src;
            f32x4 fa1 = *(const f32x4*)(src + 4);
            __hip_bfloat16 t8[8];
            t8[0] = __float2bfloat16(fa0[0]); t8[1] = __float2bfloat16(fa0[1]);
            t8[2] = __float2bfloat16(fa0[2]); t8[3] = __float2bfloat16(fa0[3]);
            t8[4] = __float2bfloat16(fa1[0]); t8[5] = __float2bfloat16(fa1[1]);
            t8[6] = __float2bfloat16(fa1[2]); t8[7] = __float2bfloat16(fa1[3]);
            *(bf16x8*)((char*)sA[buf] + oA) = *(const bf16x8*)t8;
        } else {
            gload_lds16(Ab + aBase + k0, (char*)sA[buf] + oA);
        }
        #pragma unroll
        for (int j = 0; j < BN / 128; ++j) {
            int o = j * 8192 + tid * 16;
            const __hip_bfloat16* src = Bt + (long)(o >> 6) * KI + k0 + ((o & 63) >> 1);
            gload_lds16(src, (char*)sB[buf] + o);
        }
    };

    auto compute = [&](int buf) {
        bf16x8 af[MR], bfr[4];
        #pragma unroll
        for (int mi = 0; mi < MR; ++mi)
            af[mi] = *(const bf16x8*)((const char*)sA[buf] + ((wr + mi * 16 + m) << 6) + q * 16);
        #pragma unroll
        for (int t = 0; t < 4; ++t)
            bfr[t] = *(const bf16x8*)((const char*)sB[buf] + ((wc + t * 16 + m) << 6) + q * 16);
        #pragma unroll
        for (int mi = 0; mi < MR; ++mi)
            #pragma unroll
            for (int t = 0; t < 4; ++t)
                acc[mi][t] = __builtin_amdgcn_mfma_f32_16x16x32_bf16(af[mi], bfr[t],
                                                                     acc[mi][t], 0, 0, 0);
    };

    stage(0, 0);
    __syncthreads();
    int cur = 0;
    for (int k0 = 0; k0 < KI; k0 += 32) {
        if (k0 + 32 < KI) stage(cur ^ 1, k0 + 32);
        compute(cur);
        __syncthreads();
        cur ^= 1;
    }

    if constexpr (MODE != 2) {
        #pragma unroll
        for (int mi = 0; mi < MR; ++mi) {
            #pragma unroll
            for (int t = 0; t < 4; ++t) {
                int col = wc + t * 16 + m;
                float bv = bias ? bias[col] : 0.f;
                #pragma unroll
                for (int r = 0; r < 4; ++r) {
                    long row = row0 + wr + mi * 16 + q * 4 + r;
                    if (row < N) {
                        float v = acc[mi][t][r] + bv;
                        if (doRelu) v = fmaxf(v, 0.f);
                        outB[row * ldcB + colOff + col] = __float2bfloat16(v);
                    }
                }
            }
        }
    }

    if constexpr (MODE == 2) {
        // fused +bias -> LN(128) -> L2norm -> f32 out. Block covers full 128-col rows.
        float vv[MR][4][4];
        float gcol[4], bcol[4];
        #pragma unroll
        for (int t = 0; t < 4; ++t) {
            int col = wc + t * 16 + m;
            float bb = bias[col];
            gcol[t] = gw[col]; bcol[t] = bw[col];
            #pragma unroll
            for (int mi = 0; mi < MR; ++mi)
                #pragma unroll
                for (int r = 0; r < 4; ++r) vv[mi][t][r] = acc[mi][t][r] + bb;
        }
        int wcid = wc >> 6;
        __syncthreads();
        #pragma unroll
        for (int mi = 0; mi < MR; ++mi) {
            #pragma unroll
            for (int r = 0; r < 4; ++r) {
                float s1 = vv[mi][0][r] + vv[mi][1][r] + vv[mi][2][r] + vv[mi][3][r];
                float s2 = vv[mi][0][r] * vv[mi][0][r] + vv[mi][1][r] * vv[mi][1][r]
                         + vv[mi][2][r] * vv[mi][2][r] + vv[mi][3][r] * vv[mi][3][r];
                s1 = red16(s1); s2 = red16(s2);
                if (m == 0) {
                    int lrow = wr + mi * 16 + q * 4 + r;
                    sRed[lrow * 4 + wcid * 2 + 0] = s1;
                    sRed[lrow * 4 + wcid * 2 + 1] = s2;
                }
            }
        }
        __syncthreads();
        #pragma unroll
        for (int mi = 0; mi < MR; ++mi) {
            #pragma unroll
            for (int r = 0; r < 4; ++r) {
                int lrow = wr + mi * 16 + q * 4 + r;
                float S1 = sRed[lrow * 4 + 0] + sRed[lrow * 4 + 2];
                float S2 = sRed[lrow * 4 + 1] + sRed[lrow * 4 + 3];
                float mean = S1 * (1.f / 128.f);
                float var = S2 * (1.f / 128.f) - mean * mean;
                float inv = rsqrtf(fmaxf(var, 0.f) + 1e-5f);
                float n2 = 0.f;
                #pragma unroll
                for (int t = 0; t < 4; ++t) {
                    float y = (vv[mi][t][r] - mean) * inv * gcol[t] + bcol[t];
                    vv[mi][t][r] = y;
                    n2 += y * y;
                }
                n2 = red16(n2);
                if (m == 0) sN2[lrow * 2 + wcid] = n2;
            }
        }
        __syncthreads();
        #pragma unroll
        for (int mi = 0; mi < MR; ++mi) {
            #pragma unroll
            for (int r = 0; r < 4; ++r) {
                int lrow = wr + mi * 16 + q * 4 + r;
                long row = row0 + lrow;
                float nrm = sqrtf(sN2[lrow * 2] + sN2[lrow * 2 + 1]);
                float sc = 1.f / fmaxf(nrm, 1e-12f);
                if (row < N) {
                    #pragma unroll
                    for (int t = 0; t < 4; ++t)
                        outF[row * 128 + wc + t * 16 + m] = vv[mi][t][r] * sc;
                }
            }
        }
    }
}

// ------------- merged dir GEMM: hwcat[N,512] = h @ [W_bu|W_td]^T + scores -------------
// 1024 threads = 16 waves (WM=2, WN=8), MR=4, double-buffered LDS (80 KB -> still
// 2 blocks/CU, thread-limited). A-tile staged ONCE per K-step for both weights.
__global__ __launch_bounds__(1024) void gemm_dir2(
    const __hip_bfloat16* __restrict__ Ab,   // h_buf [N,256]
    const __hip_bfloat16* __restrict__ Bt,   // Wcat [512,256] (bu rows 0-255, td 256-511)
    const float* __restrict__ asrc0, const float* __restrict__ adst0,
    const float* __restrict__ asrc1, const float* __restrict__ adst1,
    float* __restrict__ aS0, float* __restrict__ aD0,
    float* __restrict__ aS1, float* __restrict__ aD1,
    __hip_bfloat16* __restrict__ outB, int N) {
    constexpr int KI = 256;
    __shared__ __align__(16) __hip_bfloat16 sA[2][128 * 32];   // 16 KB
    __shared__ __align__(16) __hip_bfloat16 sB[2][512 * 32];   // 64 KB

    int tid = threadIdx.x;
    int wv = tid >> 6, ln = tid & 63;
    int m = ln & 15, q = ln >> 4;
    long row0 = (long)blockIdx.x * 128;
    int wr = (wv >> 3) * 64;             // 0 or 64
    int wc = (wv & 7) * 64;              // 0..448

    f32x4 acc[4][4];
    #pragma unroll
    for (int mi = 0; mi < 4; ++mi)
        #pragma unroll
        for (int t = 0; t < 4; ++t) acc[mi][t] = (f32x4){0.f, 0.f, 0.f, 0.f};

    int oA = (tid & 511) * 16;           // A staged by threads 0-511
    long rowA = row0 + (oA >> 6);
    if (rowA >= N) rowA = N - 1;
    int kel = (oA & 63) >> 1;
    long aBase = rowA * (long)KI + kel;
    int oB0 = tid * 16;                  // B: 2 chunks of 16 KB

    auto stage = [&](int buf, int k0) {
        if (tid < 512) gload_lds16(Ab + aBase + k0, (char*)sA[buf] + oA);
        #pragma unroll
        for (int j = 0; j < 2; ++j) {
            int o = j * 16384 + oB0;
            const __hip_bfloat16* src = Bt + (long)(o >> 6) * KI + k0 + ((o & 63) >> 1);
            gload_lds16(src, (char*)sB[buf] + o);
        }
    };
    auto compute = [&](int buf) {
        bf16x8 af[4], bfr[4];
        #pragma unroll
        for (int mi = 0; mi < 4; ++mi)
            af[mi] = *(const bf16x8*)((const char*)sA[buf] + ((wr + mi * 16 + m) << 6) + q * 16);
        #pragma unroll
        for (int t = 0; t < 4; ++t)
            bfr[t] = *(const bf16x8*)((const char*)sB[buf] + ((wc + t * 16 + m) << 6) + q * 16);
        #pragma unroll
        for (int mi = 0; mi < 4; ++mi)
            #pragma unroll
            for (int t = 0; t < 4; ++t)
                acc[mi][t] = __builtin_amdgcn_mfma_f32_16x16x32_bf16(af[mi], bfr[t],
                                                                     acc[mi][t], 0, 0, 0);
    };

    stage(0, 0);
    __syncthreads();
    int cur = 0;
    for (int k0 = 0; k0 < KI; k0 += 32) {
        if (k0 + 32 < KI) stage(cur ^ 1, k0 + 32);
        compute(cur);
        __syncthreads();
        cur ^= 1;
    }

    // C-write into [N,512] concat layout
    #pragma unroll
    for (int mi = 0; mi < 4; ++mi) {
        #pragma unroll
        for (int t = 0; t < 4; ++t) {
            int col = wc + t * 16 + m;
            #pragma unroll
            for (int r = 0; r < 4; ++r) {
                long row = row0 + wr + mi * 16 + q * 4 + r;
                if (row < N) outB[row * 512 + col] = __float2bfloat16(acc[mi][t][r]);
            }
        }
    }

    // fused attention scores: wave's 64 cols = (dir, head); reduce over 16 m-lanes.
    int dir = wc >> 8;
    int cc = wc & 255;
    int h = cc >> 6;
    const float* as_ = dir ? asrc1 : asrc0;
    const float* ad_ = dir ? adst1 : adst0;
    float* aS = dir ? aS1 : aS0;
    float* aD = dir ? aD1 : aD0;
    f32x4 sw, dw;
    #pragma unroll
    for (int t = 0; t < 4; ++t) {
        sw[t] = as_[cc + t * 16 + m];
        dw[t] = ad_[cc + t * 16 + m];
    }
    #pragma unroll
    for (int mi = 0; mi < 4; ++mi) {
        #pragma unroll
        for (int r = 0; r < 4; ++r) {
            float ps = acc[mi][0][r] * sw[0] + acc[mi][1][r] * sw[1]
                     + acc[mi][2][r] * sw[2] + acc[mi][3][r] * sw[3];
            float pd = acc[mi][0][r] * dw[0] + acc[mi][1][r] * dw[1]
                     + acc[mi][2][r] * dw[2] + acc[mi][3][r] * dw[3];
            ps = red16(ps); pd = red16(pd);
            long row = row0 + wr + mi * 16 + q * 4 + r;
            if (m == 0 && row < N) {
                aS[row * 4 + h] = ps;
                aD[row * 4 + h] = pd;
            }
        }
    }
}

// ---------------- CSR scans (combined 2N virtual nodes) ----------------
__global__ __launch_bounds__(256) void scan1(const int* __restrict__ cnt,
                                             int* __restrict__ offpart,
                                             int* __restrict__ bsum, int n) {
    int t = threadIdx.x, i = blockIdx.x * 256 + t;
    int lane = t & 63, w = t >> 6;
    int v = (i < n) ? cnt[i] : 0;
    int inc = v;
    #pragma unroll
    for (int o = 1; o < 64; o <<= 1) {
        int u = __shfl_up(inc, o, 64);
        if (lane >= o) inc += u;
    }
    __shared__ int wsum[4];
    if (lane == 63) wsum[w] = inc;
    __syncthreads();
    int wadd = 0;
    #pragma unroll
    for (int k = 0; k < 4; ++k) if (k < w) wadd += wsum[k];
    if (i < n) offpart[i] = inc - v + wadd;
    if (t == 255) bsum[blockIdx.x] = inc + wadd;
}

// exclusive scan of up to 2048 block sums, single block of 256 threads
__global__ __launch_bounds__(256) void scan2(const int* __restrict__ bsum,
                                             int* __restrict__ btot, int nb) {
    int t = threadIdx.x, lane = t & 63, w = t >> 6;
    int loc[8]; int s = 0;
    #pragma unroll
    for (int k = 0; k < 8; ++k) {
        int idx = t * 8 + k;
        int v = (idx < nb) ? bsum[idx] : 0;
        loc[k] = s; s += v;
    }
    int inc = s;
    #pragma unroll
    for (int o = 1; o < 64; o <<= 1) {
        int u = __shfl_up(inc, o, 64);
        if (lane >= o) inc += u;
    }
    __shared__ int wsum[4];
    if (lane == 63) wsum[w] = inc;
    __syncthreads();
    int wadd = 0;
    #pragma unroll
    for (int k = 0; k < 4; ++k) if (k < w) wadd += wsum[k];
    int excl = inc - s + wadd;
    #pragma unroll
    for (int k = 0; k < 8; ++k) {
        int idx = t * 8 + k;
        if (idx < nb) btot[idx] = excl + loc[k];
    }
}

__global__ __launch_bounds__(256) void finalize_off(const int* __restrict__ offpart,
                                                    const int* __restrict__ btot,
                                                    int* __restrict__ off, int n, int Etot) {
    int i = blockIdx.x * 256 + threadIdx.x;
    if (i < n) off[i] = offpart[i] + btot[i >> 8];
    if (i == 0) off[n] = Etot;
}

__global__ __launch_bounds__(256) void scatter_src2(const int* __restrict__ ei0,
                                                    const int* __restrict__ ei1,
                                                    int E, int N,
                                                    const int* __restrict__ off,
                                                    int* __restrict__ cur,
                                                    int* __restrict__ esrc) {
    int e = blockIdx.x * 256 + threadIdx.x;
    if (e >= 2 * E) return;
    int d, s;
    if (e < E) { d = ei0[E + e]; s = ei0[e]; }
    else       { d = ei1[e] + N; s = ei1[e - E] + N; }   // virtual ids
    int pos = off[d] + atomicAdd(&cur[d], 1);
    esrc[pos] = s;
}

// -------- gather + INLINE softmax + bias + LN + relu: 4 vnodes/wave, 16 lanes x 16ch -
// Each lane serves head = li>>2; per-head softmax stats computed serially over the
// node's (tiny, deg~1) edge list: max pass, sum pass, then gather pass applies alpha.
// hw/out are [N,512]; virtual node d: dir = d>=N, physical pd = d - dir*N.
// aS/aD are [2N][4] virtual-indexed (esrc holds virtual src ids).
__global__ __launch_bounds__(256) void gat_gather(
    const int* __restrict__ off, const int* __restrict__ esrc,
    const float* __restrict__ aS, const float* __restrict__ aD,
    const __hip_bfloat16* __restrict__ hw,
    const float* __restrict__ bias0, const float* __restrict__ g0,
    const float* __restrict__ b0,
    const float* __restrict__ bias1, const float* __restrict__ g1,
    const float* __restrict__ b1,
    __hip_bfloat16* __restrict__ out, int N) {
    int tid = threadIdx.x;
    int lane = tid & 63;
    int grp = lane >> 4, li = lane & 15;
    long d = (long)blockIdx.x * 16 + (tid >> 6) * 4 + grp;
    if (d >= 2 * (long)N) return;
    int dir = d >= N;
    long dirN = (long)dir * N;
    long pd = d - dirN;
    int dirOff = dir << 8;
    const float* bias = dir ? bias1 : bias0;
    const float* g = dir ? g1 : g0;
    const float* b = dir ? b1 : b0;
    int beg = off[d], end = off[d + 1];
    int head = li >> 2;          // 16 ch/lane -> single head per lane
    int c0 = li * 16;

    // inline per-head softmax stats (serial over edges; uniform within group)
    float adh = aD[4 * d + head];
    float es = lrelu(aS[4 * d + head] + adh);    // self-loop score
    float mh = es;
    for (int j = beg; j < end; ++j) {
        int sv = esrc[j];
        mh = fmaxf(mh, lrelu(aS[4 * (long)sv + head] + adh));
    }
    float sum = __expf(es - mh);
    for (int j = beg; j < end; ++j) {
        int sv = esrc[j];
        sum += __expf(lrelu(aS[4 * (long)sv + head] + adh) - mh);
    }
    float rsh = 1.f / sum;

    float acc[16];
    {   // self loop
        float a = __expf(es - mh) * rsh;
        const __hip_bfloat16* r = hw + pd * 512 + dirOff + c0;
        bf16x8 h0 = *(const bf16x8*)r;
        bf16x8 h1 = *(const bf16x8*)(r + 8);
        #pragma unroll
        for (int k = 0; k < 8; ++k) {
            acc[k] = a * bf2f(h0[k]);
            acc[8 + k] = a * bf2f(h1[k]);
        }
    }
    for (int j = beg; j < end; ++j) {
        int sv = esrc[j];                       // virtual src (uniform within group)
        float a = __expf(lrelu(aS[4 * (long)sv + head] + adh) - mh) * rsh;
        const __hip_bfloat16* r = hw + ((long)sv - dirN) * 512 + dirOff + c0;
        bf16x8 h0 = *(const bf16x8*)r;
        bf16x8 h1 = *(const bf16x8*)(r + 8);
        #pragma unroll
        for (int k = 0; k < 8; ++k) {
            acc[k] += a * bf2f(h0[k]);
            acc[8 + k] += a * bf2f(h1[k]);
        }
    }
    // bias + LN(256) within 16-lane group + relu
    float s1 = 0.f, s2 = 0.f;
    #pragma unroll
    for (int k = 0; k < 16; k += 4) {
        f32x4 bi = *(const f32x4*)(bias + c0 + k);
        #pragma unroll
        for (int u = 0; u < 4; ++u) {
            float v = acc[k + u] + bi[u];
            acc[k + u] = v;
            s1 += v; s2 += v * v;
        }
    }
    #pragma unroll
    for (int o = 1; o < 16; o <<= 1) {
        s1 += __shfl_xor(s1, o, 64);
        s2 += __shfl_xor(s2, o, 64);
    }
    float mean = s1 * (1.f / 256.f);
    float var = s2 * (1.f / 256.f) - mean * mean;
    float inv = rsqrtf(fmaxf(var, 0.f) + 1e-5f);
    __hip_bfloat16 o16[16];
    #pragma unroll
    for (int k = 0; k < 16; k += 4) {
        f32x4 gv = *(const f32x4*)(g + c0 + k);
        f32x4 bv = *(const f32x4*)(b + c0 + k);
        #pragma unroll
        for (int u = 0; u < 4; ++u) {
            float y = (acc[k + u] - mean) * inv * gv[u] + bv[u];
            o16[k + u] = __float2bfloat16(fmaxf(y, 0.f));
        }
    }
    __hip_bfloat16* orow = out + pd * 512 + dirOff + c0;
    *(bf16x8*)orow = *(const bf16x8*)o16;
    *(bf16x8*)(orow + 8) = *(const bf16x8*)(o16 + 8);
}

extern "C" void kernel_launch(void* const* d_in, const int* in_sizes, int n_in,
                              void* d_out, int out_size, void* d_ws, size_t ws_size,
                              hipStream_t stream) {
    const float* x      = (const float*)d_in[0];
    const int*   ei_bu  = (const int*)d_in[1];
    const int*   ei_td  = (const int*)d_in[2];
    const float* Wp     = (const float*)d_in[3];
    const float* bp     = (const float*)d_in[4];
    const float* W_bu   = (const float*)d_in[5];
    const float* asrc_bu= (const float*)d_in[6];
    const float* adst_bu= (const float*)d_in[7];
    const float* bias_bu= (const float*)d_in[8];
    const float* W_td   = (const float*)d_in[9];
    const float* asrc_td= (const float*)d_in[10];
    const float* adst_td= (const float*)d_in[11];
    const float* bias_td= (const float*)d_in[12];
    const float* Wf     = (const float*)d_in[13];
    const float* bfv    = (const float*)d_in[14];
    const float* g_bu   = (const float*)d_in[15];
    const float* b_bu   = (const float*)d_in[16];
    const float* g_td   = (const float*)d_in[17];
    const float* b_td   = (const float*)d_in[18];
    const float* g_out  = (const float*)d_in[19];
    const float* b_out  = (const float*)d_in[20];

    const int N = in_sizes[0] / HID;   // 200000
    const int E = in_sizes[1] / 2;     // 200000
    const int N2 = 2 * N, E2 = 2 * E;

    char* ws = (char*)d_ws;
    size_t off0 = 0;
    auto take = [&](size_t bytes) -> char* {
        char* p = ws + off0;
        off0 += (bytes + 255) & ~(size_t)255;
        return p;
    };
    __hip_bfloat16* h_buf = (__hip_bfloat16*)take((size_t)N * 256 * 2);
    __hip_bfloat16* hwcat = (__hip_bfloat16*)take((size_t)N * 512 * 2); // [N][bu|td]
    __hip_bfloat16* xcat  = (__hip_bfloat16*)take((size_t)N * 512 * 2); // [N][xbu|xtd]
    float* aS    = (float*)take((size_t)N2 * 16);       // [2N][4] (dir0 | dir1)
    float* aD    = (float*)take((size_t)N2 * 16);
    int* cnt     = (int*)take((size_t)N2 * 4);  // cnt and cur adjacent -> one zero pass
    int* cur     = (int*)take((size_t)N2 * 4);
    int* offpart = (int*)take((size_t)N2 * 4);
    int* offarr  = (int*)take((size_t)(N2 + 1) * 4);
    int* esrc    = (int*)take((size_t)E2 * 4);
    int* bsum    = (int*)take(2048 * 4);
    int* btot    = (int*)take(2048 * 4);
    __hip_bfloat16* Wpt  = (__hip_bfloat16*)take(256 * 256 * 2);
    __hip_bfloat16* Wcat = (__hip_bfloat16*)take(512 * 256 * 2);  // [512 KO][256 KI]
    __hip_bfloat16* Wft  = (__hip_bfloat16*)take(128 * 512 * 2);  // [128 KO][512 KI]

    // weight transposes + zero cnt/cur in one launch (grid covers max(262144, 4N))
    int nZero = N2 * 2;                               // cnt + cur ints
    int tgrid = (nZero > 262144 ? nZero : 262144);
    transpose_all<<<(tgrid + 255) / 256, 256, 0, stream>>>(
        Wp, W_bu, W_td, Wf, Wpt, Wcat, Wft, cnt, nZero);

    int gm = (N + 127) / 128;

    // h = relu(x @ Wp + bp)  + fused edge histogram (cnt zeroed by prior kernel)
    gemm_tiled<256, 0, 1><<<gm, 512, 0, stream>>>(
        x, nullptr, 256, Wpt, 256, bp, 1, h_buf, 256, 0, nullptr,
        nullptr, nullptr, ei_bu, ei_td, E, cnt, N);

    // hwcat = h @ [W_bu|W_td]  + fused a_src/a_dst scores for both dirs
    gemm_dir2<<<gm, 1024, 0, stream>>>(
        h_buf, Wcat, asrc_bu, adst_bu, asrc_td, adst_td,
        aS, aD, aS + (size_t)N * 4, aD + (size_t)N * 4, hwcat, N);

    // combined CSR over 2N virtual nodes (scan chain only; hist fused into gemm1)
    int egrid2 = (E2 + 255) / 256;
    int ngrid2 = (N2 + 255) / 256;
    scan1<<<ngrid2, 256, 0, stream>>>(cnt, offpart, bsum, N2);
    scan2<<<1, 256, 0, stream>>>(bsum, btot, ngrid2);
    finalize_off<<<ngrid2, 256, 0, stream>>>(offpart, btot, offarr, N2, E2);
    scatter_src2<<<egrid2, 256, 0, stream>>>(ei_bu, ei_td, E, N, offarr, cur, esrc);
    // gather with inline per-head softmax (att_alpha eliminated)
    gat_gather<<<(N2 + 15) / 16, 256, 0, stream>>>(offarr, esrc, aS, aD, hwcat,
                                                   bias_bu, g_bu, b_bu,
                                                   bias_td, g_td, b_td,
                                                   xcat, N);

    // final: out = L2norm(LN(xcat @ Wf + bf)) fully fused  (gw/bw MUST be non-null)
    gemm_tiled<128, 2, 0><<<gm, 512, 0, stream>>>(
        nullptr, xcat, 512, Wft, 512, bfv, 0, nullptr, 128, 0, (float*)d_out,
        g_out, b_out, nullptr, nullptr, 0, nullptr, N);
}

// Round 17
// 804.232 us; speedup vs baseline: 1.0506x; 1.0506x over previous
//
#include <hip/hip_runtime.h>
#include <hip/hip_bf16.h>
#include <stdint.h>

// HierarchicalGNN forward, FP32 in/out, MFMA bf16 GEMMs, CSR-gather GAT (no f32 atomics).
// h=relu(x@Wp+bp); two GATConv(+selfloops, softmax-per-dst) -> LN -> relu;
// concat @ Wf -> LN -> L2-normalize.
// N=200000, E=200000/dir (avg degree ~1), IN=HID=256, HEADS=4, C=64, OUT=128.
// Structure: transpose_all also zeroes cnt/cur; gemm1 prologue does the edge histogram
// (cnt zeroed by PREVIOUS kernel - stream order); ONE merged dir GEMM (gemm_dir2,
// A+B dbuf 80 KB) -> [N,512] concat + fused att scores; COMBINED 2N-virtual-node CSR
// (scan1/scan2/finalize/scatter); att_alpha (thread/vnode, PRECOMPUTED alpha -
// R16's inline softmax in gather cost +60us, reverted); gat_gather 4 vnodes/wave;
// final GEMM fused bias+LN+L2norm.
// LESSONS: B must be LDS-staged ahead (R13 -19%); counted-vmcnt regresses at 2-phase
// (R10); MODE=2 needs non-null gw/bw (R6/R7 fault); edge prefetch in gather null (R15);
// inline softmax in gather = serial scalar gathers on critical path, -40% (R16).

typedef __attribute__((ext_vector_type(8))) short bf16x8;
typedef __attribute__((ext_vector_type(4))) short bf16x4;
typedef __attribute__((ext_vector_type(4))) float f32x4;

#define HID 256

__device__ __forceinline__ float red16(float v) {   // sum within 16-lane group
    #pragma unroll
    for (int o = 1; o < 16; o <<= 1) v += __shfl_xor(v, o, 64);
    return v;
}
__device__ __forceinline__ float bf2f(short s) {
    return __uint_as_float(((unsigned)(unsigned short)s) << 16);
}

// async global->LDS, 16B per lane (global_load_lds_dwordx4).
__device__ __forceinline__ void gload_lds16(const void* g, void* l) {
    __builtin_amdgcn_global_load_lds(
        reinterpret_cast<const __attribute__((address_space(1))) uint32_t*>(
            reinterpret_cast<uintptr_t>(g)),
        reinterpret_cast<__attribute__((address_space(3))) uint32_t*>(
            reinterpret_cast<uintptr_t>(l)),
        16, 0, 0);
}

// ------- fused: all four weight transposes + zero cnt/cur, one launch -------
__global__ __launch_bounds__(256) void transpose_all(
    const float* __restrict__ Wp, const float* __restrict__ Wbu,
    const float* __restrict__ Wtd, const float* __restrict__ Wf,
    __hip_bfloat16* __restrict__ Wpt, __hip_bfloat16* __restrict__ Wcat,
    __hip_bfloat16* __restrict__ Wft, int* __restrict__ zeroPtr, int nZero) {
    int idx = blockIdx.x * 256 + threadIdx.x;
    if (idx < nZero) zeroPtr[idx] = 0;
    if (idx < 65536) {
        int k = idx >> 8, j = idx & 255;
        Wpt[j * 256 + k] = __float2bfloat16(Wp[idx]);
    } else if (idx < 131072) {
        int t = idx - 65536; int k = t >> 8, j = t & 255;
        Wcat[j * 256 + k] = __float2bfloat16(Wbu[t]);
    } else if (idx < 196608) {
        int t = idx - 131072; int k = t >> 8, j = t & 255;
        Wcat[65536 + j * 256 + k] = __float2bfloat16(Wtd[t]);
    } else if (idx < 262144) {
        int t = idx - 196608; int k = t >> 7, j = t & 127;   // KI=512, KO=128
        Wft[(long)j * 512 + k] = __float2bfloat16(Wf[t]);
    }
}

// ---------------- tiled MFMA GEMM: C[N,BN] = A[N,KI] @ Bt[BN,KI]^T ----------------
// BM=128, BK=32, double-buffered LDS (A and B); B via global_load_lds_dwordx4;
// A via gload (CVT=0) or reg-staged f32->bf16 (CVT=1). 512 threads = 8 waves.
// MODE 0: +bias/relu -> bf16 out; optional fused edge histogram in prologue.
// MODE 2: fused +bias -> LN(128) -> L2-normalize -> f32 out (BN=128)
template<int BN, int MODE, int CVT>
__global__ __launch_bounds__(512) void gemm_tiled(
    const float* __restrict__ Af, const __hip_bfloat16* __restrict__ Ab, int lda,
    const __hip_bfloat16* __restrict__ Bt, int KI,
    const float* __restrict__ bias, int doRelu,
    __hip_bfloat16* __restrict__ outB, int ldcB, int colOff,
    float* __restrict__ outF,
    const float* __restrict__ gw, const float* __restrict__ bw,
    const int* __restrict__ ei0, const int* __restrict__ ei1, int E,
    int* __restrict__ cntH, int N) {

    constexpr int WN = BN / 64;          // waves along N (4 or 2)
    constexpr int WM = 8 / WN;           // waves along M (2 or 4)
    constexpr int MR = (128 / WM) / 16;  // m-frags per wave (4 or 2)

    __shared__ __align__(16) __hip_bfloat16 sA[2][128 * 32];  // [buf][row][k] 64B rows
    __shared__ __align__(16) __hip_bfloat16 sB[2][BN * 32];   // [buf][col][k] 64B rows
    __shared__ float sRed[MODE == 2 ? 128 * 4 : 4];
    __shared__ float sN2[MODE == 2 ? 128 * 2 : 2];

    int tid = threadIdx.x;

    // fused edge histogram (MODE 0): 800K threads cover 2E=400K edges; overlaps GEMM.
    if constexpr (MODE == 0) {
        if (cntH) {
            int e = blockIdx.x * 512 + tid;
            if (e < E) atomicAdd(&cntH[ei0[E + e]], 1);
            else if (e < 2 * E) atomicAdd(&cntH[ei1[e] + N], 1);  // ei1[E+(e-E)] = dst_td
        }
    }

    int wv = tid >> 6, ln = tid & 63;
    int m = ln & 15, q = ln >> 4;
    long row0 = (long)blockIdx.x * 128;
    int wr = (wv / WN) * (128 / WM);
    int wc = (wv % WN) * 64;

    f32x4 acc[MR][4];
    #pragma unroll
    for (int mi = 0; mi < MR; ++mi)
        #pragma unroll
        for (int t = 0; t < 4; ++t) acc[mi][t] = (f32x4){0.f, 0.f, 0.f, 0.f};

    int oA = tid * 16;                   // dest byte in sA buf (8 KB total)
    long rowA = row0 + (oA >> 6);
    if (rowA >= N) rowA = N - 1;         // clamp tail loads (dup reads, safe)
    int kel = (oA & 63) >> 1;            // element offset in 32-elem k-chunk
    long aBase = rowA * (long)lda + kel;

    auto stage = [&](int buf, int k0) {
        if constexpr (CVT) {
            const float* src = Af + aBase + k0;
            f32x4 fa0 = *(const f32x4*)src;
            f32x4 fa1 = *(const f32x4*)(src + 4);
            __hip_bfloat16 t8[8];
            t8[0] = __float2bfloat16(fa0[0]); t8[1] = __float2bfloat16(fa0[1]);
            t8[2] = __float2bfloat16(fa0[2]); t8[3] = __float2bfloat16(fa0[3]);
            t8[4] = __float2bfloat16(fa1[0]); t8[5] = __float2bfloat16(fa1[1]);
            t8[6] = __float2bfloat16(fa1[2]); t8[7] = __float2bfloat16(fa1[3]);
            *(bf16x8*)((char*)sA[buf] + oA) = *(const bf16x8*)t8;
        } else {
            gload_lds16(Ab + aBase + k0, (char*)sA[buf] + oA);
        }
        #pragma unroll
        for (int j = 0; j < BN / 128; ++j) {
            int o = j * 8192 + tid * 16;
            const __hip_bfloat16* src = Bt + (long)(o >> 6) * KI + k0 + ((o & 63) >> 1);
            gload_lds16(src, (char*)sB[buf] + o);
        }
    };

    auto compute = [&](int buf) {
        bf16x8 af[MR], bfr[4];
        #pragma unroll
        for (int mi = 0; mi < MR; ++mi)
            af[mi] = *(const bf16x8*)((const char*)sA[buf] + ((wr + mi * 16 + m) << 6) + q * 16);
        #pragma unroll
        for (int t = 0; t < 4; ++t)
            bfr[t] = *(const bf16x8*)((const char*)sB[buf] + ((wc + t * 16 + m) << 6) + q * 16);
        #pragma unroll
        for (int mi = 0; mi < MR; ++mi)
            #pragma unroll
            for (int t = 0; t < 4; ++t)
                acc[mi][t] = __builtin_amdgcn_mfma_f32_16x16x32_bf16(af[mi], bfr[t],
                                                                     acc[mi][t], 0, 0, 0);
    };

    stage(0, 0);
    __syncthreads();
    int cur = 0;
    for (int k0 = 0; k0 < KI; k0 += 32) {
        if (k0 + 32 < KI) stage(cur ^ 1, k0 + 32);
        compute(cur);
        __syncthreads();
        cur ^= 1;
    }

    if constexpr (MODE != 2) {
        #pragma unroll
        for (int mi = 0; mi < MR; ++mi) {
            #pragma unroll
            for (int t = 0; t < 4; ++t) {
                int col = wc + t * 16 + m;
                float bv = bias ? bias[col] : 0.f;
                #pragma unroll
                for (int r = 0; r < 4; ++r) {
                    long row = row0 + wr + mi * 16 + q * 4 + r;
                    if (row < N) {
                        float v = acc[mi][t][r] + bv;
                        if (doRelu) v = fmaxf(v, 0.f);
                        outB[row * ldcB + colOff + col] = __float2bfloat16(v);
                    }
                }
            }
        }
    }

    if constexpr (MODE == 2) {
        // fused +bias -> LN(128) -> L2norm -> f32 out. Block covers full 128-col rows.
        float vv[MR][4][4];
        float gcol[4], bcol[4];
        #pragma unroll
        for (int t = 0; t < 4; ++t) {
            int col = wc + t * 16 + m;
            float bb = bias[col];
            gcol[t] = gw[col]; bcol[t] = bw[col];
            #pragma unroll
            for (int mi = 0; mi < MR; ++mi)
                #pragma unroll
                for (int r = 0; r < 4; ++r) vv[mi][t][r] = acc[mi][t][r] + bb;
        }
        int wcid = wc >> 6;
        __syncthreads();
        #pragma unroll
        for (int mi = 0; mi < MR; ++mi) {
            #pragma unroll
            for (int r = 0; r < 4; ++r) {
                float s1 = vv[mi][0][r] + vv[mi][1][r] + vv[mi][2][r] + vv[mi][3][r];
                float s2 = vv[mi][0][r] * vv[mi][0][r] + vv[mi][1][r] * vv[mi][1][r]
                         + vv[mi][2][r] * vv[mi][2][r] + vv[mi][3][r] * vv[mi][3][r];
                s1 = red16(s1); s2 = red16(s2);
                if (m == 0) {
                    int lrow = wr + mi * 16 + q * 4 + r;
                    sRed[lrow * 4 + wcid * 2 + 0] = s1;
                    sRed[lrow * 4 + wcid * 2 + 1] = s2;
                }
            }
        }
        __syncthreads();
        #pragma unroll
        for (int mi = 0; mi < MR; ++mi) {
            #pragma unroll
            for (int r = 0; r < 4; ++r) {
                int lrow = wr + mi * 16 + q * 4 + r;
                float S1 = sRed[lrow * 4 + 0] + sRed[lrow * 4 + 2];
                float S2 = sRed[lrow * 4 + 1] + sRed[lrow * 4 + 3];
                float mean = S1 * (1.f / 128.f);
                float var = S2 * (1.f / 128.f) - mean * mean;
                float inv = rsqrtf(fmaxf(var, 0.f) + 1e-5f);
                float n2 = 0.f;
                #pragma unroll
                for (int t = 0; t < 4; ++t) {
                    float y = (vv[mi][t][r] - mean) * inv * gcol[t] + bcol[t];
                    vv[mi][t][r] = y;
                    n2 += y * y;
                }
                n2 = red16(n2);
                if (m == 0) sN2[lrow * 2 + wcid] = n2;
            }
        }
        __syncthreads();
        #pragma unroll
        for (int mi = 0; mi < MR; ++mi) {
            #pragma unroll
            for (int r = 0; r < 4; ++r) {
                int lrow = wr + mi * 16 + q * 4 + r;
                long row = row0 + lrow;
                float nrm = sqrtf(sN2[lrow * 2] + sN2[lrow * 2 + 1]);
                float sc = 1.f / fmaxf(nrm, 1e-12f);
                if (row < N) {
                    #pragma unroll
                    for (int t = 0; t < 4; ++t)
                        outF[row * 128 + wc + t * 16 + m] = vv[mi][t][r] * sc;
                }
            }
        }
    }
}

// ------------- merged dir GEMM: hwcat[N,512] = h @ [W_bu|W_td]^T + scores -------------
// 1024 threads = 16 waves (WM=2, WN=8), MR=4, double-buffered LDS (80 KB).
__global__ __launch_bounds__(1024) void gemm_dir2(
    const __hip_bfloat16* __restrict__ Ab,   // h_buf [N,256]
    const __hip_bfloat16* __restrict__ Bt,   // Wcat [512,256]
    const float* __restrict__ asrc0, const float* __restrict__ adst0,
    const float* __restrict__ asrc1, const float* __restrict__ adst1,
    float* __restrict__ aS0, float* __restrict__ aD0,
    float* __restrict__ aS1, float* __restrict__ aD1,
    __hip_bfloat16* __restrict__ outB, int N) {
    constexpr int KI = 256;
    __shared__ __align__(16) __hip_bfloat16 sA[2][128 * 32];   // 16 KB
    __shared__ __align__(16) __hip_bfloat16 sB[2][512 * 32];   // 64 KB

    int tid = threadIdx.x;
    int wv = tid >> 6, ln = tid & 63;
    int m = ln & 15, q = ln >> 4;
    long row0 = (long)blockIdx.x * 128;
    int wr = (wv >> 3) * 64;             // 0 or 64
    int wc = (wv & 7) * 64;              // 0..448

    f32x4 acc[4][4];
    #pragma unroll
    for (int mi = 0; mi < 4; ++mi)
        #pragma unroll
        for (int t = 0; t < 4; ++t) acc[mi][t] = (f32x4){0.f, 0.f, 0.f, 0.f};

    int oA = (tid & 511) * 16;           // A staged by threads 0-511
    long rowA = row0 + (oA >> 6);
    if (rowA >= N) rowA = N - 1;
    int kel = (oA & 63) >> 1;
    long aBase = rowA * (long)KI + kel;
    int oB0 = tid * 16;                  // B: 2 chunks of 16 KB

    auto stage = [&](int buf, int k0) {
        if (tid < 512) gload_lds16(Ab + aBase + k0, (char*)sA[buf] + oA);
        #pragma unroll
        for (int j = 0; j < 2; ++j) {
            int o = j * 16384 + oB0;
            const __hip_bfloat16* src = Bt + (long)(o >> 6) * KI + k0 + ((o & 63) >> 1);
            gload_lds16(src, (char*)sB[buf] + o);
        }
    };
    auto compute = [&](int buf) {
        bf16x8 af[4], bfr[4];
        #pragma unroll
        for (int mi = 0; mi < 4; ++mi)
            af[mi] = *(const bf16x8*)((const char*)sA[buf] + ((wr + mi * 16 + m) << 6) + q * 16);
        #pragma unroll
        for (int t = 0; t < 4; ++t)
            bfr[t] = *(const bf16x8*)((const char*)sB[buf] + ((wc + t * 16 + m) << 6) + q * 16);
        #pragma unroll
        for (int mi = 0; mi < 4; ++mi)
            #pragma unroll
            for (int t = 0; t < 4; ++t)
                acc[mi][t] = __builtin_amdgcn_mfma_f32_16x16x32_bf16(af[mi], bfr[t],
                                                                     acc[mi][t], 0, 0, 0);
    };

    stage(0, 0);
    __syncthreads();
    int cur = 0;
    for (int k0 = 0; k0 < KI; k0 += 32) {
        if (k0 + 32 < KI) stage(cur ^ 1, k0 + 32);
        compute(cur);
        __syncthreads();
        cur ^= 1;
    }

    // C-write into [N,512] concat layout
    #pragma unroll
    for (int mi = 0; mi < 4; ++mi) {
        #pragma unroll
        for (int t = 0; t < 4; ++t) {
            int col = wc + t * 16 + m;
            #pragma unroll
            for (int r = 0; r < 4; ++r) {
                long row = row0 + wr + mi * 16 + q * 4 + r;
                if (row < N) outB[row * 512 + col] = __float2bfloat16(acc[mi][t][r]);
            }
        }
    }

    // fused attention scores: wave's 64 cols = (dir, head); reduce over 16 m-lanes.
    int dir = wc >> 8;
    int cc = wc & 255;
    int h = cc >> 6;
    const float* as_ = dir ? asrc1 : asrc0;
    const float* ad_ = dir ? adst1 : adst0;
    float* aS = dir ? aS1 : aS0;
    float* aD = dir ? aD1 : aD0;
    f32x4 sw, dw;
    #pragma unroll
    for (int t = 0; t < 4; ++t) {
        sw[t] = as_[cc + t * 16 + m];
        dw[t] = ad_[cc + t * 16 + m];
    }
    #pragma unroll
    for (int mi = 0; mi < 4; ++mi) {
        #pragma unroll
        for (int r = 0; r < 4; ++r) {
            float ps = acc[mi][0][r] * sw[0] + acc[mi][1][r] * sw[1]
                     + acc[mi][2][r] * sw[2] + acc[mi][3][r] * sw[3];
            float pd = acc[mi][0][r] * dw[0] + acc[mi][1][r] * dw[1]
                     + acc[mi][2][r] * dw[2] + acc[mi][3][r] * dw[3];
            ps = red16(ps); pd = red16(pd);
            long row = row0 + wr + mi * 16 + q * 4 + r;
            if (m == 0 && row < N) {
                aS[row * 4 + h] = ps;
                aD[row * 4 + h] = pd;
            }
        }
    }
}

// ---------------- CSR scans (combined 2N virtual nodes) ----------------
__global__ __launch_bounds__(256) void scan1(const int* __restrict__ cnt,
                                             int* __restrict__ offpart,
                                             int* __restrict__ bsum, int n) {
    int t = threadIdx.x, i = blockIdx.x * 256 + t;
    int lane = t & 63, w = t >> 6;
    int v = (i < n) ? cnt[i] : 0;
    int inc = v;
    #pragma unroll
    for (int o = 1; o < 64; o <<= 1) {
        int u = __shfl_up(inc, o, 64);
        if (lane >= o) inc += u;
    }
    __shared__ int wsum[4];
    if (lane == 63) wsum[w] = inc;
    __syncthreads();
    int wadd = 0;
    #pragma unroll
    for (int k = 0; k < 4; ++k) if (k < w) wadd += wsum[k];
    if (i < n) offpart[i] = inc - v + wadd;
    if (t == 255) bsum[blockIdx.x] = inc + wadd;
}

// exclusive scan of up to 2048 block sums, single block of 256 threads
__global__ __launch_bounds__(256) void scan2(const int* __restrict__ bsum,
                                             int* __restrict__ btot, int nb) {
    int t = threadIdx.x, lane = t & 63, w = t >> 6;
    int loc[8]; int s = 0;
    #pragma unroll
    for (int k = 0; k < 8; ++k) {
        int idx = t * 8 + k;
        int v = (idx < nb) ? bsum[idx] : 0;
        loc[k] = s; s += v;
    }
    int inc = s;
    #pragma unroll
    for (int o = 1; o < 64; o <<= 1) {
        int u = __shfl_up(inc, o, 64);
        if (lane >= o) inc += u;
    }
    __shared__ int wsum[4];
    if (lane == 63) wsum[w] = inc;
    __syncthreads();
    int wadd = 0;
    #pragma unroll
    for (int k = 0; k < 4; ++k) if (k < w) wadd += wsum[k];
    int excl = inc - s + wadd;
    #pragma unroll
    for (int k = 0; k < 8; ++k) {
        int idx = t * 8 + k;
        if (idx < nb) btot[idx] = excl + loc[k];
    }
}

__global__ __launch_bounds__(256) void finalize_off(const int* __restrict__ offpart,
                                                    const int* __restrict__ btot,
                                                    int* __restrict__ off, int n, int Etot) {
    int i = blockIdx.x * 256 + threadIdx.x;
    if (i < n) off[i] = offpart[i] + btot[i >> 8];
    if (i == 0) off[n] = Etot;
}

__global__ __launch_bounds__(256) void scatter_src2(const int* __restrict__ ei0,
                                                    const int* __restrict__ ei1,
                                                    int E, int N,
                                                    const int* __restrict__ off,
                                                    int* __restrict__ cur,
                                                    int* __restrict__ esrc) {
    int e = blockIdx.x * 256 + threadIdx.x;
    if (e >= 2 * E) return;
    int d, s;
    if (e < E) { d = ei0[E + e]; s = ei0[e]; }
    else       { d = ei1[e] + N; s = ei1[e - E] + N; }   // virtual ids
    int pos = off[d] + atomicAdd(&cur[d], 1);
    esrc[pos] = s;
}

// ---------------- per-dst softmax -> alpha (thread per virtual node) ----------------
__global__ __launch_bounds__(256) void att_alpha(
    const int* __restrict__ off, const int* __restrict__ esrc,
    const float* __restrict__ a_s, const float* __restrict__ a_d,
    float* __restrict__ alpha_self, float* __restrict__ alpha_e, int N2) {
    int d = blockIdx.x * 256 + threadIdx.x;
    if (d >= N2) return;
    int beg = off[d], end = off[d + 1];
    f32x4 adv = *(const f32x4*)(a_d + 4 * (long)d);
    f32x4 asd = *(const f32x4*)(a_s + 4 * (long)d);
    float es[4], m[4];
    #pragma unroll
    for (int h = 0; h < 4; ++h) {
        float e = asd[h] + adv[h]; e = e > 0.f ? e : 0.2f * e;
        es[h] = e; m[h] = e;
    }
    for (int j = beg; j < end; ++j) {
        int s = esrc[j];
        f32x4 asv = *(const f32x4*)(a_s + 4 * (long)s);
        #pragma unroll
        for (int h = 0; h < 4; ++h) {
            float e = asv[h] + adv[h]; e = e > 0.f ? e : 0.2f * e;
            m[h] = fmaxf(m[h], e);
        }
    }
    float sum[4];
    #pragma unroll
    for (int h = 0; h < 4; ++h) sum[h] = __expf(es[h] - m[h]);
    for (int j = beg; j < end; ++j) {
        int s = esrc[j];
        f32x4 asv = *(const f32x4*)(a_s + 4 * (long)s);
        #pragma unroll
        for (int h = 0; h < 4; ++h) {
            float e = asv[h] + adv[h]; e = e > 0.f ? e : 0.2f * e;
            sum[h] += __expf(e - m[h]);
        }
    }
    float rs[4];
    #pragma unroll
    for (int h = 0; h < 4; ++h) rs[h] = 1.f / sum[h];
    f32x4 sa;
    #pragma unroll
    for (int h = 0; h < 4; ++h) sa[h] = __expf(es[h] - m[h]) * rs[h];
    *(f32x4*)(alpha_self + 4 * (long)d) = sa;
    for (int j = beg; j < end; ++j) {
        int s = esrc[j];
        f32x4 asv = *(const f32x4*)(a_s + 4 * (long)s);
        f32x4 av;
        #pragma unroll
        for (int h = 0; h < 4; ++h) {
            float e = asv[h] + adv[h]; e = e > 0.f ? e : 0.2f * e;
            av[h] = __expf(e - m[h]) * rs[h];
        }
        *(f32x4*)(alpha_e + 4 * (long)j) = av;
    }
}

// -------- gather + bias + LN + relu: 4 virtual nodes/wave, 16 lanes x 16ch --------
// hw/out are [N,512]; virtual node d: dir = d>=N, physical pd = d - dir*N.
__global__ __launch_bounds__(256) void gat_gather(
    const int* __restrict__ off, const int* __restrict__ esrc,
    const float* __restrict__ alpha_self, const float* __restrict__ alpha_e,
    const __hip_bfloat16* __restrict__ hw,
    const float* __restrict__ bias0, const float* __restrict__ g0,
    const float* __restrict__ b0,
    const float* __restrict__ bias1, const float* __restrict__ g1,
    const float* __restrict__ b1,
    __hip_bfloat16* __restrict__ out, int N) {
    int tid = threadIdx.x;
    int lane = tid & 63;
    int grp = lane >> 4, li = lane & 15;
    long d = (long)blockIdx.x * 16 + (tid >> 6) * 4 + grp;
    if (d >= 2 * (long)N) return;
    int dir = d >= N;
    long dirN = (long)dir * N;
    long pd = d - dirN;
    int dirOff = dir << 8;
    const float* bias = dir ? bias1 : bias0;
    const float* g = dir ? g1 : g0;
    const float* b = dir ? b1 : b0;
    int beg = off[d], end = off[d + 1];
    int head = li >> 2;          // 16 ch/lane -> single head per lane
    int c0 = li * 16;
    float acc[16];
    {   // self loop
        float a = alpha_self[4 * d + head];
        const __hip_bfloat16* r = hw + pd * 512 + dirOff + c0;
        bf16x8 h0 = *(const bf16x8*)r;
        bf16x8 h1 = *(const bf16x8*)(r + 8);
        #pragma unroll
        for (int k = 0; k < 8; ++k) {
            acc[k] = a * bf2f(h0[k]);
            acc[8 + k] = a * bf2f(h1[k]);
        }
    }
    for (int j = beg; j < end; ++j) {
        long s = esrc[j] - dirN;                // physical src (uniform within group)
        float a = alpha_e[4 * (long)j + head];
        const __hip_bfloat16* r = hw + s * 512 + dirOff + c0;
        bf16x8 h0 = *(const bf16x8*)r;
        bf16x8 h1 = *(const bf16x8*)(r + 8);
        #pragma unroll
        for (int k = 0; k < 8; ++k) {
            acc[k] += a * bf2f(h0[k]);
            acc[8 + k] += a * bf2f(h1[k]);
        }
    }
    // bias + LN(256) within 16-lane group + relu
    float s1 = 0.f, s2 = 0.f;
    #pragma unroll
    for (int k = 0; k < 16; k += 4) {
        f32x4 bi = *(const f32x4*)(bias + c0 + k);
        #pragma unroll
        for (int u = 0; u < 4; ++u) {
            float v = acc[k + u] + bi[u];
            acc[k + u] = v;
            s1 += v; s2 += v * v;
        }
    }
    #pragma unroll
    for (int o = 1; o < 16; o <<= 1) {
        s1 += __shfl_xor(s1, o, 64);
        s2 += __shfl_xor(s2, o, 64);
    }
    float mean = s1 * (1.f / 256.f);
    float var = s2 * (1.f / 256.f) - mean * mean;
    float inv = rsqrtf(fmaxf(var, 0.f) + 1e-5f);
    __hip_bfloat16 o16[16];
    #pragma unroll
    for (int k = 0; k < 16; k += 4) {
        f32x4 gv = *(const f32x4*)(g + c0 + k);
        f32x4 bv = *(const f32x4*)(b + c0 + k);
        #pragma unroll
        for (int u = 0; u < 4; ++u) {
            float y = (acc[k + u] - mean) * inv * gv[u] + bv[u];
            o16[k + u] = __float2bfloat16(fmaxf(y, 0.f));
        }
    }
    __hip_bfloat16* orow = out + pd * 512 + dirOff + c0;
    *(bf16x8*)orow = *(const bf16x8*)o16;
    *(bf16x8*)(orow + 8) = *(const bf16x8*)(o16 + 8);
}

extern "C" void kernel_launch(void* const* d_in, const int* in_sizes, int n_in,
                              void* d_out, int out_size, void* d_ws, size_t ws_size,
                              hipStream_t stream) {
    const float* x      = (const float*)d_in[0];
    const int*   ei_bu  = (const int*)d_in[1];
    const int*   ei_td  = (const int*)d_in[2];
    const float* Wp     = (const float*)d_in[3];
    const float* bp     = (const float*)d_in[4];
    const float* W_bu   = (const float*)d_in[5];
    const float* asrc_bu= (const float*)d_in[6];
    const float* adst_bu= (const float*)d_in[7];
    const float* bias_bu= (const float*)d_in[8];
    const float* W_td   = (const float*)d_in[9];
    const float* asrc_td= (const float*)d_in[10];
    const float* adst_td= (const float*)d_in[11];
    const float* bias_td= (const float*)d_in[12];
    const float* Wf     = (const float*)d_in[13];
    const float* bfv    = (const float*)d_in[14];
    const float* g_bu   = (const float*)d_in[15];
    const float* b_bu   = (const float*)d_in[16];
    const float* g_td   = (const float*)d_in[17];
    const float* b_td   = (const float*)d_in[18];
    const float* g_out  = (const float*)d_in[19];
    const float* b_out  = (const float*)d_in[20];

    const int N = in_sizes[0] / HID;   // 200000
    const int E = in_sizes[1] / 2;     // 200000
    const int N2 = 2 * N, E2 = 2 * E;

    char* ws = (char*)d_ws;
    size_t off0 = 0;
    auto take = [&](size_t bytes) -> char* {
        char* p = ws + off0;
        off0 += (bytes + 255) & ~(size_t)255;
        return p;
    };
    __hip_bfloat16* h_buf = (__hip_bfloat16*)take((size_t)N * 256 * 2);
    __hip_bfloat16* hwcat = (__hip_bfloat16*)take((size_t)N * 512 * 2); // [N][bu|td]
    __hip_bfloat16* xcat  = (__hip_bfloat16*)take((size_t)N * 512 * 2); // [N][xbu|xtd]
    float* aS    = (float*)take((size_t)N2 * 16);       // [2N][4] (dir0 | dir1)
    float* aD    = (float*)take((size_t)N2 * 16);
    float* alsf  = (float*)take((size_t)N2 * 16);       // alpha_self [2N][4]
    float* ale   = (float*)take((size_t)E2 * 16);       // alpha_e [2E][4] (CSR order)
    int* cnt     = (int*)take((size_t)N2 * 4);  // cnt and cur adjacent -> one zero pass
    int* cur     = (int*)take((size_t)N2 * 4);
    int* offpart = (int*)take((size_t)N2 * 4);
    int* offarr  = (int*)take((size_t)(N2 + 1) * 4);
    int* esrc    = (int*)take((size_t)E2 * 4);
    int* bsum    = (int*)take(2048 * 4);
    int* btot    = (int*)take(2048 * 4);
    __hip_bfloat16* Wpt  = (__hip_bfloat16*)take(256 * 256 * 2);
    __hip_bfloat16* Wcat = (__hip_bfloat16*)take(512 * 256 * 2);  // [512 KO][256 KI]
    __hip_bfloat16* Wft  = (__hip_bfloat16*)take(128 * 512 * 2);  // [128 KO][512 KI]

    // weight transposes + zero cnt/cur in one launch
    int nZero = N2 * 2;                               // cnt + cur ints
    int tgrid = (nZero > 262144 ? nZero : 262144);
    transpose_all<<<(tgrid + 255) / 256, 256, 0, stream>>>(
        Wp, W_bu, W_td, Wf, Wpt, Wcat, Wft, cnt, nZero);

    int gm = (N + 127) / 128;

    // h = relu(x @ Wp + bp)  + fused edge histogram (cnt zeroed by prior kernel)
    gemm_tiled<256, 0, 1><<<gm, 512, 0, stream>>>(
        x, nullptr, 256, Wpt, 256, bp, 1, h_buf, 256, 0, nullptr,
        nullptr, nullptr, ei_bu, ei_td, E, cnt, N);

    // hwcat = h @ [W_bu|W_td]  + fused a_src/a_dst scores for both dirs
    gemm_dir2<<<gm, 1024, 0, stream>>>(
        h_buf, Wcat, asrc_bu, adst_bu, asrc_td, adst_td,
        aS, aD, aS + (size_t)N * 4, aD + (size_t)N * 4, hwcat, N);

    // combined CSR over 2N virtual nodes (scan chain; hist fused into gemm1)
    int egrid2 = (E2 + 255) / 256;
    int ngrid2 = (N2 + 255) / 256;
    scan1<<<ngrid2, 256, 0, stream>>>(cnt, offpart, bsum, N2);
    scan2<<<1, 256, 0, stream>>>(bsum, btot, ngrid2);
    finalize_off<<<ngrid2, 256, 0, stream>>>(offpart, btot, offarr, N2, E2);
    scatter_src2<<<egrid2, 256, 0, stream>>>(ei_bu, ei_td, E, N, offarr, cur, esrc);
    // softmax (thread/vnode, PRECOMPUTED alpha), then gather + bias + LN + relu
    att_alpha<<<ngrid2, 256, 0, stream>>>(offarr, esrc, aS, aD, alsf, ale, N2);
    gat_gather<<<(N2 + 15) / 16, 256, 0, stream>>>(offarr, esrc, alsf, ale, hwcat,
                                                   bias_bu, g_bu, b_bu,
                                                   bias_td, g_td, b_td,
                                                   xcat, N);

    // final: out = L2norm(LN(xcat @ Wf + bf)) fully fused  (gw/bw MUST be non-null)
    gemm_tiled<128, 2, 0><<<gm, 512, 0, stream>>>(
        nullptr, xcat, 512, Wft, 512, bfv, 0, nullptr, 128, 0, (float*)d_out,
        g_out, b_out, nullptr, nullptr, 0, nullptr, N);
}